// Round 5
// baseline (230.045 us; speedup 1.0000x reference)
//
#include <hip/hip_runtime.h>
#include <math.h>

// Problem dims (fixed)
#define NB 16
#define NV 12
#define NROWS 192          // NB*NV
#define DRAW 200704
#define KOUT 256
#define DFEAT 1024
#define NG 8
#define NCLS 40

// K1: 512 blocks = 256 K-chunks x 2 col-halves. KC=784 -> 25 steps of BK=32.
#define NCHUNK 256
#define KC 784

// per-LDS-buffer offsets (bytes): A 12 tiles x 2048 (1KB hi + 1KB lo), B 8 x 2048
#define ABASE 0
#define BBASE 24576
#define BUFSZ 40960        // x2 buffers = 81920 = exactly 2 blocks/CU

// workspace layout (bytes)
#define WS_P     0                       // [192][256] f32 (atomic accumulator)
#define WS_DESC  196608                  // [16][1024] f32
#define WS_Z1    262144                  // [16][512] f32
#define WS_Z2    294912                  // [16][256] f32

typedef __attribute__((ext_vector_type(8))) short short8;
typedef __attribute__((ext_vector_type(4))) float f32x4;

__global__ __launch_bounds__(256) void k0_zero(float* __restrict__ P) {
    P[blockIdx.x * 256 + threadIdx.x] = 0.f;
}

// split x -> hi(bf16 trunc) + lo(bf16 trunc of exact residual); pack 4 elems
__device__ __forceinline__ void cvt4(float4 v, uint2& hi, uint2& lo) {
    unsigned b0 = __float_as_uint(v.x), b1 = __float_as_uint(v.y);
    unsigned b2 = __float_as_uint(v.z), b3 = __float_as_uint(v.w);
    hi.x = (b0 >> 16) | (b1 & 0xffff0000u);
    hi.y = (b2 >> 16) | (b3 & 0xffff0000u);
    float r0 = v.x - __uint_as_float(b0 & 0xffff0000u);
    float r1 = v.y - __uint_as_float(b1 & 0xffff0000u);
    float r2 = v.z - __uint_as_float(b2 & 0xffff0000u);
    float r3 = v.w - __uint_as_float(b3 & 0xffff0000u);
    lo.x = (__float_as_uint(r0) >> 16) | (__float_as_uint(r1) & 0xffff0000u);
    lo.y = (__float_as_uint(r2) >> 16) | (__float_as_uint(r3) & 0xffff0000u);
}

// issue step-S1 global loads into named reg buffers
#define K1_LOAD(DA, DB, S1)                                                    \
  {                                                                            \
    const int koff = (S1) * 32;                                                \
    _Pragma("unroll") for (int p = 0; p < 3; ++p) {                            \
      bool ok = aact[p] && (akq[p] * 4 + koff < KC);                           \
      DA[p] = ok ? *(const float4*)(aptr[p] + koff)                            \
                 : make_float4(0.f, 0.f, 0.f, 0.f);                            \
    }                                                                          \
    _Pragma("unroll") for (int q = 0; q < 8; ++q) {                            \
      int dd = bkh * 8 + q + koff;                                             \
      DB[q] = (dd < KC) ? bptr[(size_t)(koff + q) * KOUT] : 0.f;               \
    }                                                                          \
  }

// cvt regs -> LDS buffer WB (compile-time 0 or BUFSZ)
#define K1_WRITE(CA, CB, WB)                                                   \
  {                                                                            \
    _Pragma("unroll") for (int p = 0; p < 3; ++p) {                            \
      uint2 hi, lo; cvt4(CA[p], hi, lo);                                       \
      *(uint2*)(smem + (WB) + awoff[p]) = hi;                                  \
      *(uint2*)(smem + (WB) + awoff[p] + 1024) = lo;                           \
    }                                                                          \
    {                                                                          \
      uint2 h0, l0, h1, l1;                                                    \
      cvt4(make_float4(CB[0], CB[1], CB[2], CB[3]), h0, l0);                   \
      cvt4(make_float4(CB[4], CB[5], CB[6], CB[7]), h1, l1);                   \
      uint4 hv; hv.x = h0.x; hv.y = h0.y; hv.z = h1.x; hv.w = h1.y;            \
      uint4 lv; lv.x = l0.x; lv.y = l0.y; lv.z = l1.x; lv.w = l1.y;            \
      *(uint4*)(smem + (WB) + bwoff) = hv;                                     \
      *(uint4*)(smem + (WB) + bwoff + 1024) = lv;                              \
    }                                                                          \
  }

// fragment reads from buffer RB + 36 MFMAs
#define K1_MMA(RB)                                                             \
  {                                                                            \
    short8 ah[3], al[3];                                                       \
    _Pragma("unroll") for (int tm = 0; tm < 3; ++tm) {                         \
      int off = (RB) + ABASE + (wm * 3 + tm) * 2048 + aroff;                   \
      ah[tm] = *(const short8*)(smem + off);                                   \
      al[tm] = *(const short8*)(smem + off + 1024);                            \
    }                                                                          \
    _Pragma("unroll") for (int tn = 0; tn < 4; ++tn) {                         \
      int off = (RB) + BBASE + (wn * 4 + tn) * 2048 +                          \
                ((lane << 4) ^ ((tn & 1) << 6));                               \
      short8 bh = *(const short8*)(smem + off);                                \
      short8 bl = *(const short8*)(smem + off + 1024);                         \
      _Pragma("unroll") for (int tm = 0; tm < 3; ++tm) {                       \
        acc[tm][tn] = __builtin_amdgcn_mfma_f32_16x16x32_bf16(ah[tm], bh, acc[tm][tn], 0, 0, 0); \
        acc[tm][tn] = __builtin_amdgcn_mfma_f32_16x16x32_bf16(ah[tm], bl, acc[tm][tn], 0, 0, 0); \
        acc[tm][tn] = __builtin_amdgcn_mfma_f32_16x16x32_bf16(al[tm], bh, acc[tm][tn], 0, 0, 0); \
      }                                                                        \
    }                                                                          \
  }

// one K-step, SINGLE barrier: MFMA reads RB while writes target WB (disjoint)
// -> ds_writes overlap MFMA issue; loads for S+2 stay in flight across the
// barrier (no vmcnt drain anywhere in the loop).
#define K1_STEP(CA, CB, NA, NB_, RB, WB, S, DOLOAD, DOWRITE)                   \
  {                                                                            \
    if (DOLOAD) K1_LOAD(NA, NB_, (S) + 2);                                     \
    if (DOWRITE) K1_WRITE(CA, CB, WB);                                         \
    K1_MMA(RB);                                                                \
    asm volatile("s_waitcnt lgkmcnt(0)" ::: "memory");                         \
    __builtin_amdgcn_s_barrier();                                              \
    __builtin_amdgcn_sched_barrier(0);                                         \
  }

// MFMA split-K/split-N GEMM, atomic-accumulate into P[192][256].
// Co-XCD bid map: both col-halves of a chunk share bid%8 (same XCD).
// 512 thr = 8 waves 4(M)x2(N); wave owns 48 rows x 64 cols = 3x4 fragments.
// bf16x3: acc += ah*bh + ah*bl + al*bh (f32 accumulate in MFMA).
__global__ __launch_bounds__(512, 4)
void k1_mfma(const float* __restrict__ raw, const float* __restrict__ W1,
             const int* __restrict__ vnum, float* __restrict__ P)
{
    __shared__ __align__(16) char smem[2 * BUFSZ];
    const int t = threadIdx.x;
    const int g8 = blockIdx.x & 7;
    const int i8 = blockIdx.x >> 3;
    const int c = g8 * 32 + (i8 >> 1);
    const int colbase = (i8 & 1) * 128;
    const int d0 = c * KC;

    // ---- A staging geometry: 3 passes, idx=p*512+t: row=idx>>3, kq=idx&7 ----
    int akq[3];
    bool aact[3];
    const float* aptr[3];
    int awoff[3];
#pragma unroll
    for (int p = 0; p < 3; ++p) {
        int idx = p * 512 + t;
        int row = idx >> 3, kq = idx & 7;
        akq[p] = kq;
        aact[p] = (row % NV) < vnum[row / NV];
        aptr[p] = raw + (size_t)row * DRAW + d0 + kq * 4;
        int off = ABASE + (row >> 4) * 2048 + (((row & 15) + ((kq >> 1) << 4)) << 4) + ((kq & 1) << 3);
        off ^= ((kq >> 1) & 1) << 6;
        awoff[p] = off;
    }
    // ---- B staging: col = t&127 (within half), kgroup bkh = t>>7 (8 k each) ----
    const int bcol = t & 127;
    const int bkh = t >> 7;
    const float* bptr = W1 + (size_t)(d0 + bkh * 8) * KOUT + colbase + bcol;
    const int bTN = bcol >> 4;
    int bwoff = BBASE + bTN * 2048 + (((bcol & 15) + (bkh << 4)) << 4);
    bwoff ^= (bTN & 1) << 6;

    // wave/fragment geometry
    const int lane = t & 63;
    const int wave = t >> 6;
    const int wm = wave >> 1, wn = wave & 1;
    const int aroff = (lane << 4) ^ (((lane >> 4) & 1) << 6);

    f32x4 acc[3][4];
#pragma unroll
    for (int i = 0; i < 3; ++i)
#pragma unroll
        for (int j = 0; j < 4; ++j) acc[i][j] = (f32x4){0.f, 0.f, 0.f, 0.f};

    float4 A0[3], A1[3];
    float B0r[8], B1r[8];
    // prologue: data(0)->A0, data(1)->A1; stage data(0) into buf0
    K1_LOAD(A0, B0r, 0);
    K1_LOAD(A1, B1r, 1);
    K1_WRITE(A0, B0r, 0);
    asm volatile("s_waitcnt lgkmcnt(0)" ::: "memory");
    __builtin_amdgcn_s_barrier();
    __builtin_amdgcn_sched_barrier(0);

    // steps 0..21 (pairs), 22 (last load), 23 (last write), 24 (MFMA only)
#pragma unroll 1
    for (int sp = 0; sp < 11; ++sp) {
        K1_STEP(A1, B1r, A0, B0r, 0, BUFSZ, 2 * sp, 1, 1);
        K1_STEP(A0, B0r, A1, B1r, BUFSZ, 0, 2 * sp + 1, 1, 1);
    }
    K1_STEP(A1, B1r, A0, B0r, 0, BUFSZ, 22, 1, 1);
    K1_STEP(A0, B0r, A1, B1r, BUFSZ, 0, 23, 0, 1);
    K1_STEP(A1, B1r, A0, B0r, 0, BUFSZ, 24, 0, 0);

    // ---- epilogue: atomic accumulate; C/D layout col=lane&15, row=(lane>>4)*4+r
#pragma unroll
    for (int tm = 0; tm < 3; ++tm) {
        int row0 = wm * 48 + tm * 16 + ((lane >> 4) << 2);
#pragma unroll
        for (int tn = 0; tn < 4; ++tn) {
            int col = colbase + wn * 64 + tn * 16 + (lane & 15);
            f32x4 a = acc[tm][tn];
#pragma unroll
            for (int r = 0; r < 4; ++r)
                atomicAdd(&P[(size_t)(row0 + r) * KOUT + col], a[r]);
        }
    }
}

// fused tail stage 1: per-sample score head + binning + coeff + desc.
// One 512-thread block per sample.
__global__ __launch_bounds__(512)
void ktail(const float* __restrict__ P, const float* __restrict__ b1,
           const float* __restrict__ W2, const float* __restrict__ b2,
           const int* __restrict__ vnum, const float* __restrict__ fv,
           float* __restrict__ desc)
{
    const int n = blockIdx.x, t = threadIdx.x;
    __shared__ float red2[NV][4];
    __shared__ float sc_s[NV], coeffL[NV], wsum[NG], wt[NG], wtotS;
    __shared__ int cnt[NG];
    const int col = t & 255;
    const int rh = t >> 8;          // row-half: which of 2 rows this iter
    const int wq = (t >> 6) & 3;    // wave quarter within the row's 4 waves
    const float b1c = b1[col], w2c = W2[col];
    // ---- scores for 12 rows: h=relu(P+b1); val=h*W2; wave+LDS reduce ----
#pragma unroll
    for (int i = 0; i < 6; ++i) {
        int v = 2 * i + rh;
        float s = P[(size_t)(n * NV + v) * KOUT + col];
        float val = fmaxf(s + b1c, 0.f) * w2c;
        for (int o = 32; o > 0; o >>= 1) val += __shfl_down(val, o, 64);
        if ((t & 63) == 0) red2[v][wq] = val;
    }
    __syncthreads();
    if (t < NV) {
        float sraw = fmaxf(red2[t][0] + red2[t][1] + red2[t][2] + red2[t][3] + b2[0], 0.f);
        sc_s[t] = 1.f / (1.f + expf(-tanhf(fabsf(sraw))));
    }
    if (t < NG) { cnt[t] = 0; wsum[t] = 0.f; }
    __syncthreads();
    // ---- binning -> coeff ----
    const int vn = vnum[n];
    const bool act = (t < NV) && (t < vn);
    float sc = 0.f; int b = 0;
    if (act) {
        sc = sc_s[t];
        b = (int)floorf(sc * 8.f); b = b < 0 ? 0 : (b > 7 ? 7 : b);
        atomicAdd(&cnt[b], 1);
    }
    __syncthreads();
    if (act) atomicAdd(&wsum[b], ceilf(sc * (float)cnt[b]));
    __syncthreads();
    if (t < NG) wt[t] = (cnt[t] > 0) ? wsum[t] / (float)cnt[t] : 0.f;
    __syncthreads();
    if (t == 0) { float x = 0.f; for (int g = 0; g < NG; ++g) x += wt[g]; wtotS = x; }
    __syncthreads();
    if (t < NV) coeffL[t] = act ? wt[b] / ((float)cnt[b] * wtotS) : 0.f;
    __syncthreads();
    // ---- desc = sum_v coeff[v]*fv[n][v][:] ----
#pragma unroll
    for (int p = 0; p < 2; ++p) {
        int d = t + p * 512;
        float a = 0.f;
#pragma unroll
        for (int v = 0; v < NV; ++v)
            a = fmaf(coeffL[v], fv[((size_t)n * NV + v) * DFEAT + d], a);
        desc[n * DFEAT + d] = a;
    }
}

// z1 = relu(desc @ Wf1 + bf1): j-sliced blocks, all 16 samples inside the
// block -> Wf1 read exactly once overall. block 512 = 64 j x 8 sample-pairs.
__global__ __launch_bounds__(512)
void kz1(const float* __restrict__ desc, const float* __restrict__ Wf1,
         const float* __restrict__ bf1, float* __restrict__ z1)
{
    __shared__ float dL[NB * DFEAT];
    const int t = threadIdx.x;
#pragma unroll
    for (int i = 0; i < 8; ++i)
        *(float4*)&dL[(i * 512 + t) * 4] = *(const float4*)&desc[(i * 512 + t) * 4];
    __syncthreads();
    const int j = blockIdx.x * 64 + (t & 63);
    const int n0 = (t >> 6) * 2;
    float a0 = 0.f, a1 = 0.f, a2 = 0.f, a3 = 0.f;
#pragma unroll 4
    for (int d = 0; d < DFEAT; d += 2) {
        float w0 = Wf1[(size_t)d * 512 + j];
        float w1 = Wf1[(size_t)(d + 1) * 512 + j];
        a0 = fmaf(dL[n0 * DFEAT + d], w0, a0);
        a1 = fmaf(dL[(n0 + 1) * DFEAT + d], w0, a1);
        a2 = fmaf(dL[n0 * DFEAT + d + 1], w1, a2);
        a3 = fmaf(dL[(n0 + 1) * DFEAT + d + 1], w1, a3);
    }
    z1[n0 * 512 + j] = fmaxf(a0 + a2 + bf1[j], 0.f);
    z1[(n0 + 1) * 512 + j] = fmaxf(a1 + a3 + bf1[j], 0.f);
}

// z2 = relu(z1 @ Wf2 + bf2): same j-sliced pattern over K=512.
__global__ __launch_bounds__(512)
void kz2(const float* __restrict__ z1, const float* __restrict__ Wf2,
         const float* __restrict__ bf2, float* __restrict__ z2)
{
    __shared__ float zL[NB * 512];
    const int t = threadIdx.x;
#pragma unroll
    for (int i = 0; i < 4; ++i)
        *(float4*)&zL[(i * 512 + t) * 4] = *(const float4*)&z1[(i * 512 + t) * 4];
    __syncthreads();
    const int j = blockIdx.x * 64 + (t & 63);
    const int n0 = (t >> 6) * 2;
    float a0 = 0.f, a1 = 0.f, a2 = 0.f, a3 = 0.f;
#pragma unroll 4
    for (int d = 0; d < 512; d += 2) {
        float w0 = Wf2[(size_t)d * 256 + j];
        float w1 = Wf2[(size_t)(d + 1) * 256 + j];
        a0 = fmaf(zL[n0 * 512 + d], w0, a0);
        a1 = fmaf(zL[(n0 + 1) * 512 + d], w0, a1);
        a2 = fmaf(zL[n0 * 512 + d + 1], w1, a2);
        a3 = fmaf(zL[(n0 + 1) * 512 + d + 1], w1, a3);
    }
    z2[n0 * 256 + j] = fmaxf(a0 + a2 + bf2[j], 0.f);
    z2[(n0 + 1) * 256 + j] = fmaxf(a1 + a3 + bf2[j], 0.f);
}

// out = z2 @ Wl + bl (z2 already relu'd)
__global__ __launch_bounds__(640)
void kout(const float* __restrict__ z2, const float* __restrict__ Wl,
          const float* __restrict__ bl, float* __restrict__ out)
{
    const int t = threadIdx.x;
    const int n = t / NCLS, j = t % NCLS;
    float a = 0.f;
    for (int d = 0; d < 256; ++d)
        a = fmaf(z2[n * 256 + d], Wl[d * NCLS + j], a);
    out[t] = a + bl[j];
}

extern "C" void kernel_launch(void* const* d_in, const int* in_sizes, int n_in,
                              void* d_out, int out_size, void* d_ws, size_t ws_size,
                              hipStream_t stream)
{
    const float* raw  = (const float*)d_in[0];
    const float* fv   = (const float*)d_in[1];
    const int*   vnum = (const int*)d_in[2];
    const float* W1   = (const float*)d_in[3];
    const float* b1   = (const float*)d_in[4];
    const float* W2   = (const float*)d_in[5];
    const float* b2   = (const float*)d_in[6];
    const float* Wf1  = (const float*)d_in[7];
    const float* bf1  = (const float*)d_in[8];
    const float* Wf2  = (const float*)d_in[9];
    const float* bf2  = (const float*)d_in[10];
    const float* Wl   = (const float*)d_in[11];
    const float* bl   = (const float*)d_in[12];
    float* out = (float*)d_out;
    char* ws = (char*)d_ws;
    float* P    = (float*)(ws + WS_P);
    float* desc = (float*)(ws + WS_DESC);
    float* z1   = (float*)(ws + WS_Z1);
    float* z2   = (float*)(ws + WS_Z2);

    k0_zero<<<NROWS, 256, 0, stream>>>(P);
    k1_mfma<<<2 * NCHUNK, 512, 0, stream>>>(raw, W1, vnum, P);
    ktail<<<NB, 512, 0, stream>>>(P, b1, W2, b2, vnum, fv, desc);
    kz1<<<8, 512, 0, stream>>>(desc, Wf1, bf1, z1);
    kz2<<<4, 512, 0, stream>>>(z1, Wf2, bf2, z2);
    kout<<<1, 640, 0, stream>>>(z2, Wl, bl, out);
}